// Round 2
// baseline (3991.897 us; speedup 1.0000x reference)
//
#include <hip/hip_runtime.h>

namespace {

constexpr int kDim    = 192;
constexpr int kHeads  = 6;
constexpr int kHd     = 32;
constexpr int kWs     = 8;
constexpr int kSs     = 4;
constexpr int kN      = 64;    // tokens per window
constexpr int kH      = 256;
constexpr int kW      = 256;
constexpr int kNwSide = 32;    // 256/8
constexpr int kBatch  = 4;
constexpr int kWindows = kBatch * kNwSide * kNwSide;  // 4096
constexpr float kScale = 0.17677669529663687f;        // 32^-0.5

constexpr int kThreads = 512;

// LDS row paddings (chosen for float4 alignment + bank spread)
constexpr int PX = 68;  // xw: channel-major [192][68]
constexpr int PQ = 36;  // qh/vh/oh: token-major [64][36]
constexpr int PK = 68;  // kt: d-major [32][68]
constexpr int PS = 68;  // sc: [64][68]

__global__ __launch_bounds__(kThreads)
void swin_fused(const float* __restrict__ x,
                const float* __restrict__ qkv_w,
                const float* __restrict__ qkv_b,
                const float* __restrict__ proj_w,
                const float* __restrict__ proj_b,
                const float* __restrict__ rpb,
                float* __restrict__ out)
{
    __shared__ float xw[kDim][PX];   // window input (ch-major); reused for output
    __shared__ float qh[kN][PQ];     // q * scale, token-major
    __shared__ float kt[kHd][PK];    // k transposed: [d][token]
    __shared__ float vh[kN][PQ];     // v, token-major
    __shared__ float sc[kN][PS];     // softmax probs
    __shared__ float oh[kN][PQ];     // per-head attention output
    __shared__ int   rgn[kN];        // shift-mask region id per token

    const int t   = threadIdx.x;
    const int win = blockIdx.x;
    const int b   = win >> 10;
    const int wh  = (win >> 5) & 31;
    const int wwi = win & 31;

    // ---------- Phase A: gather shifted window into LDS -------------------
    // roll(-SS): shifted[hs] = x[(hs+SS) mod 256]
    for (int idx = t; idx < kN * kDim; idx += kThreads) {
        const int ch = idx >> 6;
        const int n  = idx & 63;
        const int r = n >> 3, c = n & 7;
        const int h = (wh * kWs + r + kSs) & (kH - 1);
        const int w = (wwi * kWs + c + kSs) & (kW - 1);
        xw[ch][n] = x[(((size_t)b * kDim + ch) * kH + h) * kW + w];
    }
    if (t < kN) {
        const int r = t >> 3, c = t & 7;
        const int hs = wh * kWs + r;
        const int ws = wwi * kWs + c;
        const int rg = (hs < kH - kWs) ? 0 : ((hs < kH - kSs) ? 1 : 2);
        const int cg = (ws < kW - kWs) ? 0 : ((ws < kW - kSs) ? 1 : 2);
        rgn[t] = rg * 3 + cg;
    }

    // final accumulators: thread owns tokens {2dtn,2dtn+1} x cols 12dtc..12dtc+11
    const int dtn = t >> 4;
    const int dtc = t & 15;
    float facc[2][12];
    #pragma unroll
    for (int i = 0; i < 2; ++i)
        #pragma unroll
        for (int j = 0; j < 12; ++j) facc[i][j] = 0.f;

    __syncthreads();

    for (int hd = 0; hd < kHeads; ++hd) {
        // ---------- Phase B: q,k,v for this head (64x96 GEMM, K=192) ------
        {
            const int tn = t & 15;   // tokens 4tn..4tn+3
            const int tj = t >> 4;   // jj cols 3tj..3tj+2 of [0,96)
            const float* wp[3];
            float acc[4][3];
            #pragma unroll
            for (int j = 0; j < 3; ++j) {
                const int jj = 3 * tj + j;
                const int which = jj >> 5;
                const int d = jj & 31;
                const int row = which * kDim + hd * kHd + d;
                wp[j] = qkv_w + (size_t)row * kDim;
                const float bias = qkv_b[row];
                #pragma unroll
                for (int i = 0; i < 4; ++i) acc[i][j] = bias;
            }
            for (int ch = 0; ch < kDim; ch += 4) {
                float xa[4][4];
                #pragma unroll
                for (int k = 0; k < 4; ++k) {
                    const float4 v = *(const float4*)&xw[ch + k][4 * tn];
                    xa[k][0] = v.x; xa[k][1] = v.y; xa[k][2] = v.z; xa[k][3] = v.w;
                }
                #pragma unroll
                for (int j = 0; j < 3; ++j) {
                    const float4 wv = *(const float4*)(wp[j] + ch);
                    #pragma unroll
                    for (int i = 0; i < 4; ++i) {
                        acc[i][j] = fmaf(xa[0][i], wv.x, acc[i][j]);
                        acc[i][j] = fmaf(xa[1][i], wv.y, acc[i][j]);
                        acc[i][j] = fmaf(xa[2][i], wv.z, acc[i][j]);
                        acc[i][j] = fmaf(xa[3][i], wv.w, acc[i][j]);
                    }
                }
            }
            #pragma unroll
            for (int j = 0; j < 3; ++j) {
                const int jj = 3 * tj + j;
                const int which = jj >> 5;
                const int d = jj & 31;
                #pragma unroll
                for (int i = 0; i < 4; ++i) {
                    const int n = 4 * tn + i;
                    const float v = acc[i][j];
                    if (which == 0)      qh[n][d] = v * kScale;
                    else if (which == 1) kt[d][n] = v;
                    else                 vh[n][d] = v;
                }
            }
        }
        __syncthreads();

        // ---------- Phase C: S = qk^T + bias + mask; softmax --------------
        {
            const int tq = t >> 4;  // rows 2tq, 2tq+1
            const int tk = t & 15;  // cols 4tk..4tk+3
            float s[2][4];
            #pragma unroll
            for (int i = 0; i < 2; ++i)
                #pragma unroll
                for (int j = 0; j < 4; ++j) s[i][j] = 0.f;

            #pragma unroll
            for (int d = 0; d < kHd; d += 4) {
                float qv[2][4], kv[4][4];
                #pragma unroll
                for (int i = 0; i < 2; ++i) {
                    const float4 v = *(const float4*)&qh[2 * tq + i][d];
                    qv[i][0] = v.x; qv[i][1] = v.y; qv[i][2] = v.z; qv[i][3] = v.w;
                }
                #pragma unroll
                for (int dd = 0; dd < 4; ++dd) {
                    const float4 v = *(const float4*)&kt[d + dd][4 * tk];
                    kv[dd][0] = v.x; kv[dd][1] = v.y; kv[dd][2] = v.z; kv[dd][3] = v.w;
                }
                #pragma unroll
                for (int i = 0; i < 2; ++i)
                    #pragma unroll
                    for (int j = 0; j < 4; ++j)
                        #pragma unroll
                        for (int dd = 0; dd < 4; ++dd)
                            s[i][j] = fmaf(qv[i][dd], kv[dd][j], s[i][j]);
            }

            // relative-position bias + shift mask (both derived analytically)
            #pragma unroll
            for (int i = 0; i < 2; ++i) {
                const int nq = 2 * tq + i;
                const int qr = nq >> 3, qc = nq & 7;
                const int rq = rgn[nq];
                #pragma unroll
                for (int j = 0; j < 4; ++j) {
                    const int nk = 4 * tk + j;
                    const int kr = nk >> 3, kc = nk & 7;
                    const int rpi = (qr - kr + 7) * 15 + (qc - kc + 7);
                    float add = rpb[rpi * kHeads + hd];
                    if (rgn[nk] != rq) add -= 100.f;
                    s[i][j] += add;
                }
            }

            // softmax: each row pair lives across 16 consecutive lanes
            float mx[2], sm[2];
            #pragma unroll
            for (int i = 0; i < 2; ++i)
                mx[i] = fmaxf(fmaxf(s[i][0], s[i][1]), fmaxf(s[i][2], s[i][3]));
            #pragma unroll
            for (int off = 8; off >= 1; off >>= 1) {
                mx[0] = fmaxf(mx[0], __shfl_xor(mx[0], off, 16));
                mx[1] = fmaxf(mx[1], __shfl_xor(mx[1], off, 16));
            }
            #pragma unroll
            for (int i = 0; i < 2; ++i) {
                sm[i] = 0.f;
                #pragma unroll
                for (int j = 0; j < 4; ++j) {
                    s[i][j] = __expf(s[i][j] - mx[i]);
                    sm[i] += s[i][j];
                }
            }
            #pragma unroll
            for (int off = 8; off >= 1; off >>= 1) {
                sm[0] += __shfl_xor(sm[0], off, 16);
                sm[1] += __shfl_xor(sm[1], off, 16);
            }
            #pragma unroll
            for (int i = 0; i < 2; ++i) {
                const float inv = 1.f / sm[i];
                const int nq = 2 * tq + i;
                #pragma unroll
                for (int j = 0; j < 4; ++j)
                    sc[nq][4 * tk + j] = s[i][j] * inv;
            }
        }
        __syncthreads();

        // ---------- Phase PV: oh = P @ V ----------------------------------
        {
            const int nq = t >> 3;
            const int td = t & 7;   // d = 4td..4td+3
            float acc[4] = {0.f, 0.f, 0.f, 0.f};
            #pragma unroll
            for (int m = 0; m < kN; m += 4) {
                const float4 p = *(const float4*)&sc[nq][m];
                const float pv[4] = {p.x, p.y, p.z, p.w};
                #pragma unroll
                for (int mm = 0; mm < 4; ++mm) {
                    const float4 v = *(const float4*)&vh[m + mm][4 * td];
                    acc[0] = fmaf(pv[mm], v.x, acc[0]);
                    acc[1] = fmaf(pv[mm], v.y, acc[1]);
                    acc[2] = fmaf(pv[mm], v.z, acc[2]);
                    acc[3] = fmaf(pv[mm], v.w, acc[3]);
                }
            }
            *(float4*)&oh[nq][4 * td] = make_float4(acc[0], acc[1], acc[2], acc[3]);
        }
        __syncthreads();

        // ---------- Phase D: facc += oh @ proj_w[:, head-slab]^T ----------
        // (proj is linear in heads: rank-32 update per head)
        {
            const float* pp = proj_w + (size_t)(12 * dtc) * kDim + hd * kHd;
            #pragma unroll
            for (int d = 0; d < kHd; d += 4) {
                float ov[2][4];
                #pragma unroll
                for (int i = 0; i < 2; ++i) {
                    const float4 v = *(const float4*)&oh[2 * dtn + i][d];
                    ov[i][0] = v.x; ov[i][1] = v.y; ov[i][2] = v.z; ov[i][3] = v.w;
                }
                #pragma unroll
                for (int j = 0; j < 12; ++j) {
                    const float4 wv = *(const float4*)(pp + (size_t)j * kDim + d);
                    #pragma unroll
                    for (int i = 0; i < 2; ++i) {
                        facc[i][j] = fmaf(ov[i][0], wv.x, facc[i][j]);
                        facc[i][j] = fmaf(ov[i][1], wv.y, facc[i][j]);
                        facc[i][j] = fmaf(ov[i][2], wv.z, facc[i][j]);
                        facc[i][j] = fmaf(ov[i][3], wv.w, facc[i][j]);
                    }
                }
            }
        }
        // no barrier needed: next Phase B touches qh/kt/vh/xw only, and the
        // barrier after it orders everything before next PV rewrites oh.
    }

    // ---------- epilogue: restage to LDS, coalesced-ish scatter -----------
    #pragma unroll
    for (int j = 0; j < 12; ++j)
        #pragma unroll
        for (int i = 0; i < 2; ++i)
            xw[12 * dtc + j][2 * dtn + i] = facc[i][j];
    __syncthreads();

    // reverse shift: final[h] = shifted[(h-SS) mod] => h = (hs+SS) mod
    for (int idx = t; idx < kN * kDim; idx += kThreads) {
        const int ch = idx >> 6;
        const int n  = idx & 63;
        const int r = n >> 3, c = n & 7;
        const int h = (wh * kWs + r + kSs) & (kH - 1);
        const int w = (wwi * kWs + c + kSs) & (kW - 1);
        out[(((size_t)b * kDim + ch) * kH + h) * kW + w] = xw[ch][n] + proj_b[ch];
    }
}

} // namespace

extern "C" void kernel_launch(void* const* d_in, const int* in_sizes, int n_in,
                              void* d_out, int out_size, void* d_ws, size_t ws_size,
                              hipStream_t stream) {
    (void)in_sizes; (void)n_in; (void)d_ws; (void)ws_size; (void)out_size;
    const float* x      = (const float*)d_in[0];
    const float* qkv_w  = (const float*)d_in[1];
    const float* qkv_b  = (const float*)d_in[2];
    const float* proj_w = (const float*)d_in[3];
    const float* proj_b = (const float*)d_in[4];
    const float* rpb    = (const float*)d_in[5];
    float* out = (float*)d_out;

    swin_fused<<<kWindows, kThreads, 0, stream>>>(
        x, qkv_w, qkv_b, proj_w, proj_b, rpb, out);
}

// Round 3
// 747.734 us; speedup vs baseline: 5.3387x; 5.3387x over previous
//
#include <hip/hip_runtime.h>

namespace {

typedef float floatx4 __attribute__((ext_vector_type(4)));
typedef short bf16x8  __attribute__((ext_vector_type(8)));

constexpr int   kThreads = 384;          // 6 waves; wave == head
constexpr float kScale   = 0.17677669529663687f;  // 32^-0.5

// float -> bf16 (RNE), bit-exact manual to avoid any type-interop risk
__device__ inline short f2bf(float f){
    unsigned u = __builtin_bit_cast(unsigned, f);
    unsigned r = (u + 0x7fffu + ((u >> 16) & 1u)) >> 16;
    return (short)r;
}

__device__ inline floatx4 mfma16(bf16x8 a, bf16x8 b, floatx4 c){
    return __builtin_amdgcn_mfma_f32_16x16x32_bf16(a, b, c, 0, 0, 0);
}

// Weight fragment for lane-group grp, K-step cs: 8 bf16 covering
// cols 32*cs + 4*grp + {0..3} and 32*cs + 16 + 4*grp + {0..3}  (the g-map).
__device__ inline bf16x8 ldwfrag(const float* wrow, const short* prow,
                                 int use_pk, int cs, int grp){
    if (use_pk){
        return *(const bf16x8*)(prow + cs * 32 + grp * 8);
    }
    const float* p = wrow + cs * 32 + grp * 4;
    float4 a = *(const float4*)p;
    float4 b = *(const float4*)(p + 16);
    bf16x8 r;
    r[0] = f2bf(a.x); r[1] = f2bf(a.y); r[2] = f2bf(a.z); r[3] = f2bf(a.w);
    r[4] = f2bf(b.x); r[5] = f2bf(b.y); r[6] = f2bf(b.z); r[7] = f2bf(b.w);
    return r;
}

// Pre-pack qkv_w (rows 0..575) and proj_w (rows 576..767) into bf16,
// fragment-ordered so one dwordx4 = one operand fragment.
__global__ void pack_w(const float* __restrict__ qkv_w,
                       const float* __restrict__ proj_w,
                       short* __restrict__ wpk){
    int idx = blockIdx.x * 256 + threadIdx.x;
    if (idx >= 768 * 192) return;
    int row = idx / 192, c = idx % 192;
    float v = (row < 576) ? qkv_w[row * 192 + c] : proj_w[(row - 576) * 192 + c];
    int cs = c >> 5, c5 = c & 31;
    int grp = (c5 & 15) >> 2;
    int j = (c5 & 3) | ((c5 >> 4) << 2);
    wpk[row * 192 + cs * 32 + grp * 8 + j] = f2bf(v);
}

__global__ __launch_bounds__(kThreads)
void swin_mfma(const float* __restrict__ x, const float* __restrict__ qkv_w,
               const float* __restrict__ qkv_b, const float* __restrict__ proj_w,
               const float* __restrict__ proj_b, const float* __restrict__ rpb,
               float* __restrict__ out, const short* __restrict__ wpk, int use_pk)
{
    // X fragments: [cs(6)][token-tile(4)][lane(64)][j(8)] bf16
    __shared__ __align__(16) short xf[6][4][64][8];
    // O fragments (per head) for the proj GEMM, same fragment order
    __shared__ __align__(16) short of[6][4][64][8];
    __shared__ float rpb_s[1350];   // 225 x 6
    __shared__ float qb_s[576];
    __shared__ float pb_s[192];
    __shared__ int   rgn_s[64];

    const int t      = threadIdx.x;
    const int lane   = t & 63;
    const int wv     = t >> 6;        // wave id == head id
    const int tok_lo = lane & 15;
    const int grp    = lane >> 4;

    const int win = blockIdx.x;
    const int b = win >> 10, wh = (win >> 5) & 31, ww = win & 31;

    // ------------- Phase A: stage tables + X fragments -------------------
    for (int i = t; i < 1350; i += kThreads) rpb_s[i] = rpb[i];
    for (int i = t; i < 576;  i += kThreads) qb_s[i]  = qkv_b[i];
    if (t < 192) pb_s[t] = proj_b[t];
    if (t < 64){
        int r = t >> 3, c = t & 7;
        int hs = wh * 8 + r, wsx = ww * 8 + c;
        int rg = (hs < 248) ? 0 : ((hs < 252) ? 1 : 2);
        int cg = (wsx < 248) ? 0 : ((wsx < 252) ? 1 : 2);
        rgn_s[t] = rg * 3 + cg;
    }
    {
        const size_t xbase = (size_t)b * 192 * 65536;
        #pragma unroll
        for (int c0 = 0; c0 < 4; ++c0){
            int comb = c0 * 6 + wv;            // 0..23, all covered by 6 waves
            int cs = comb >> 2, tt = comb & 3;
            int tok = tok_lo + 16 * tt;
            int rr = tok >> 3, cc = tok & 7;
            int h = (wh * 8 + rr + 4) & 255;   // roll(-4)
            int w = (ww * 8 + cc + 4) & 255;
            const float* xp = x + xbase + h * 256 + w;
            bf16x8 f;
            #pragma unroll
            for (int j = 0; j < 8; ++j){
                int ch = 32 * cs + 4 * grp + (j & 3) + 16 * (j >> 2);
                f[j] = f2bf(xp[(size_t)ch << 16]);
            }
            *(bf16x8*)&xf[cs][tt][lane][0] = f;
        }
    }
    __syncthreads();

    const int hd = wv;

    // ------------- QKV GEMMs (transposed Q,K; direct V) ------------------
    floatx4 qa[2][4], ka[2][4], va[4][2];
    {
        floatx4 z = {0.f, 0.f, 0.f, 0.f};
        #pragma unroll
        for (int o = 0; o < 2; ++o)
            #pragma unroll
            for (int tt = 0; tt < 4; ++tt){ qa[o][tt] = z; ka[o][tt] = z; va[tt][o] = z; }
    }
    const int rq0 = 32 * hd + tok_lo;
    #pragma unroll
    for (int cs = 0; cs < 6; ++cs){
        bf16x8 wq[2], wk[2], wvv[2];
        #pragma unroll
        for (int o = 0; o < 2; ++o){
            int r1 = rq0 + 16 * o;
            wq[o]  = ldwfrag(qkv_w + (size_t)r1 * 192,         wpk + (size_t)r1 * 192,         use_pk, cs, grp);
            wk[o]  = ldwfrag(qkv_w + (size_t)(192 + r1) * 192, wpk + (size_t)(192 + r1) * 192, use_pk, cs, grp);
            wvv[o] = ldwfrag(qkv_w + (size_t)(384 + r1) * 192, wpk + (size_t)(384 + r1) * 192, use_pk, cs, grp);
        }
        #pragma unroll
        for (int tt = 0; tt < 4; ++tt){
            bf16x8 xb = *(const bf16x8*)&xf[cs][tt][lane][0];
            qa[0][tt] = mfma16(wq[0], xb, qa[0][tt]);   // D[qch][token]
            qa[1][tt] = mfma16(wq[1], xb, qa[1][tt]);
            ka[0][tt] = mfma16(wk[0], xb, ka[0][tt]);   // D[kch][token]
            ka[1][tt] = mfma16(wk[1], xb, ka[1][tt]);
            va[tt][0] = mfma16(xb, wvv[0], va[tt][0]);  // D[token][vch]
            va[tt][1] = mfma16(xb, wvv[1], va[tt][1]);
        }
    }

    // ------------- bias add + pack Q/K/V operand fragments ---------------
    bf16x8 Qf[4], Kf[4], Vf[2][2];
    {
        float qb[8], kb[8];
        #pragma unroll
        for (int j = 0; j < 8; ++j){
            int d = 16 * (j >> 2) + 4 * grp + (j & 3);
            qb[j] = qb_s[32 * hd + d];
            kb[j] = qb_s[192 + 32 * hd + d];
        }
        #pragma unroll
        for (int tt = 0; tt < 4; ++tt){
            bf16x8 fq, fk;
            #pragma unroll
            for (int j = 0; j < 8; ++j){
                int o = j >> 2, r = j & 3;
                fq[j] = f2bf((qa[o][tt][r] + qb[j]) * kScale);
                fk[j] = f2bf( ka[o][tt][r] + kb[j]);
            }
            Qf[tt] = fq; Kf[tt] = fk;
        }
        #pragma unroll
        for (int it = 0; it < 2; ++it){
            float vb = qb_s[384 + 32 * hd + 16 * it + tok_lo];
            #pragma unroll
            for (int ks = 0; ks < 2; ++ks){
                bf16x8 f;
                #pragma unroll
                for (int j = 0; j < 8; ++j){
                    int r = j & 3, tt = 2 * ks + (j >> 2);
                    f[j] = f2bf(va[tt][it][r] + vb);
                }
                Vf[it][ks] = f;
            }
        }
    }

    // ------------- S = K·Q^T (swapped => D[key][query]) -------------------
    float s[4][4][4];                      // [kt][qt][reg]
    {
        floatx4 z = {0.f, 0.f, 0.f, 0.f};
        #pragma unroll
        for (int kt = 0; kt < 4; ++kt)
            #pragma unroll
            for (int qt = 0; qt < 4; ++qt){
                floatx4 sv = mfma16(Kf[kt], Qf[qt], z);
                #pragma unroll
                for (int r = 0; r < 4; ++r) s[kt][qt][r] = sv[r];
            }
    }
    // bias + shift-mask (analytic rpi; validated in round 2)
    {
        const int qrb = tok_lo >> 3, qc = tok_lo & 7;
        const int krb = grp >> 1,    kc0 = 4 * (grp & 1);
        int rq[4];
        #pragma unroll
        for (int qt = 0; qt < 4; ++qt) rq[qt] = rgn_s[16 * qt + tok_lo];
        #pragma unroll
        for (int kt = 0; kt < 4; ++kt){
            int rk[4];
            #pragma unroll
            for (int r = 0; r < 4; ++r) rk[r] = rgn_s[16 * kt + 4 * grp + r];
            #pragma unroll
            for (int qt = 0; qt < 4; ++qt){
                int base = (2 * qt + qrb - 2 * kt - krb + 7) * 15 + (qc - kc0 + 7);
                #pragma unroll
                for (int r = 0; r < 4; ++r){
                    float add = rpb_s[(base - r) * 6 + hd];
                    if (rk[r] != rq[qt]) add -= 100.f;
                    s[kt][qt][r] += add;
                }
            }
        }
    }
    // softmax over keys: 16 local vals + shfl_xor(16), shfl_xor(32)
    float inv[4];
    #pragma unroll
    for (int qt = 0; qt < 4; ++qt){
        float m = -1e30f;
        #pragma unroll
        for (int kt = 0; kt < 4; ++kt)
            #pragma unroll
            for (int r = 0; r < 4; ++r) m = fmaxf(m, s[kt][qt][r]);
        m = fmaxf(m, __shfl_xor(m, 16));
        m = fmaxf(m, __shfl_xor(m, 32));
        float sum = 0.f;
        #pragma unroll
        for (int kt = 0; kt < 4; ++kt)
            #pragma unroll
            for (int r = 0; r < 4; ++r){
                float e = __expf(s[kt][qt][r] - m);
                s[kt][qt][r] = e; sum += e;
            }
        sum += __shfl_xor(sum, 16);
        sum += __shfl_xor(sum, 32);
        inv[qt] = 1.0f / sum;
    }

    // ------------- O^T = V^T·P  (D[d][query]) -----------------------------
    floatx4 oa[2][4];
    {
        floatx4 z = {0.f, 0.f, 0.f, 0.f};
        #pragma unroll
        for (int it = 0; it < 2; ++it)
            #pragma unroll
            for (int qt = 0; qt < 4; ++qt) oa[it][qt] = z;
    }
    #pragma unroll
    for (int ks = 0; ks < 2; ++ks)
        #pragma unroll
        for (int qt = 0; qt < 4; ++qt){
            bf16x8 pf;
            #pragma unroll
            for (int j = 0; j < 8; ++j) pf[j] = f2bf(s[2 * ks + (j >> 2)][qt][j & 3]);
            oa[0][qt] = mfma16(Vf[0][ks], pf, oa[0][qt]);
            oa[1][qt] = mfma16(Vf[1][ks], pf, oa[1][qt]);
        }
    // normalize + stage O fragments for proj
    #pragma unroll
    for (int qt = 0; qt < 4; ++qt){
        bf16x8 f;
        #pragma unroll
        for (int j = 0; j < 8; ++j){
            int it = j >> 2, r = j & 3;
            f[j] = f2bf(oa[it][qt][r] * inv[qt]);
        }
        *(bf16x8*)&of[wv][qt][lane][0] = f;
    }
    __syncthreads();

    // ------------- proj: D[och][token], each wave owns 32 och -------------
    floatx4 pa[2][4];
    {
        floatx4 z = {0.f, 0.f, 0.f, 0.f};
        #pragma unroll
        for (int o = 0; o < 2; ++o)
            #pragma unroll
            for (int tt = 0; tt < 4; ++tt) pa[o][tt] = z;
    }
    #pragma unroll
    for (int h2 = 0; h2 < 6; ++h2){
        bf16x8 pw[2];
        #pragma unroll
        for (int o = 0; o < 2; ++o){
            int och = 32 * wv + 16 * o + tok_lo;
            pw[o] = ldwfrag(proj_w + (size_t)och * 192,
                            wpk + (size_t)(576 + och) * 192, use_pk, h2, grp);
        }
        #pragma unroll
        for (int tt = 0; tt < 4; ++tt){
            bf16x8 ob = *(const bf16x8*)&of[h2][tt][lane][0];
            pa[0][tt] = mfma16(pw[0], ob, pa[0][tt]);
            pa[1][tt] = mfma16(pw[1], ob, pa[1][tt]);
        }
    }

    // ------------- epilogue: bias + reverse-shift scatter -----------------
    #pragma unroll
    for (int o = 0; o < 2; ++o)
        #pragma unroll
        for (int tt = 0; tt < 4; ++tt){
            int tok = tok_lo + 16 * tt;
            int rr = tok >> 3, cc = tok & 7;
            int h = (wh * 8 + rr + 4) & 255;
            int w = (ww * 8 + cc + 4) & 255;
            #pragma unroll
            for (int r = 0; r < 4; ++r){
                int och = 32 * wv + 16 * o + 4 * grp + r;
                out[((size_t)(b * 192 + och) << 16) + (h << 8) + w]
                    = pa[o][tt][r] + pb_s[och];
            }
        }
}

} // namespace

extern "C" void kernel_launch(void* const* d_in, const int* in_sizes, int n_in,
                              void* d_out, int out_size, void* d_ws, size_t ws_size,
                              hipStream_t stream) {
    (void)in_sizes; (void)n_in; (void)out_size;
    const float* x      = (const float*)d_in[0];
    const float* qkv_w  = (const float*)d_in[1];
    const float* qkv_b  = (const float*)d_in[2];
    const float* proj_w = (const float*)d_in[3];
    const float* proj_b = (const float*)d_in[4];
    const float* rpb    = (const float*)d_in[5];
    float* out = (float*)d_out;
    short* wpk = (short*)d_ws;

    const int use_pk = (ws_size >= (size_t)(768 * 192 * 2)) ? 1 : 0;
    if (use_pk) pack_w<<<576, 256, 0, stream>>>(qkv_w, proj_w, wpk);
    swin_mfma<<<4096, kThreads, 0, stream>>>(x, qkv_w, qkv_b, proj_w, proj_b,
                                             rpb, out, wpk, use_pk);
}